// Round 5
// baseline (118.979 us; speedup 1.0000x reference)
//
#include <hip/hip_runtime.h>
#include <hip/hip_bf16.h>
#include <stdint.h>

typedef __attribute__((ext_vector_type(8))) __bf16 bf16x8;
typedef __attribute__((ext_vector_type(16))) float floatx16;

#if __has_builtin(__builtin_amdgcn_exp2f)
#define EXP2F(x) __builtin_amdgcn_exp2f(x)
#else
#define EXP2F(x) exp2f(x)
#endif

// sqrt(2*log2(e)): baked into normalized rows so dot = 2*log2(e)*cos and
// sim = exp2(dot) = exp(cos/0.5) with zero epilogue multiplies.
#define SCALE_SQRT 1.69864359f

// ---------------- prep: int64-probe labels + normalize -----------------------
__global__ __launch_bounds__(256) void k_prep(const float* __restrict__ x,
                                              const int* __restrict__ raw,
                                              ushort* __restrict__ xb,
                                              unsigned char* __restrict__ lab8,
                                              int N) {
  const int row = (blockIdx.x * 256 + threadIdx.x) >> 6;  // one wave per row
  const int lane = threadIdx.x & 63;
  if (row >= N) return;
  // parallel int64 detection: odd words all zero => labels are int64
  const int probe = raw[2 * lane + 1];
  const bool is64 = (__ballot(probe != 0) == 0ull);
  const float2 v = ((const float2*)(x + (size_t)row * 128))[lane];
  float ss = v.x * v.x + v.y * v.y;
#pragma unroll
  for (int m = 1; m < 64; m <<= 1) ss += __shfl_xor(ss, m, 64);
  const float rn = SCALE_SQRT / fmaxf(sqrtf(ss), 1e-12f);
  __hip_bfloat162 o;
  o.x = __float2bfloat16(v.x * rn);
  o.y = __float2bfloat16(v.y * rn);
  ((__hip_bfloat162*)xb)[row * 64 + lane] = o;
  // labels are 0..63 -> byte-pack (lossless)
  if (lane == 0) lab8[row] = (unsigned char)(is64 ? raw[2 * row] : raw[row]);
}

// ---------------- main: LDS-free symmetric upper-triangle --------------------
// One 128x128 pair (s,u), u>=s, per block (2080 blocks, dynamically packed).
// xb is 2 MB = L2-resident, and the MFMA B-fragment has the IDENTICAL per-lane
// layout as the A-fragment (row jb0+h*32+l31, k-slice (kt*2+g2)*8) — so B is
// read straight from L2, like A. No ldsB, no global_load_lds, no swizzle, no
// vmcnt choreography; ONE barrier (col-flush combine via 4 KB scratch).
// Occupancy is VGPR-bound (~3 blocks/CU x 4 waves = 12 waves/CU) instead of
// LDS-stage-bound (2 blocks/CU in R0-R4) -> TLP finally hides latency.
// Row sums of pair (s,u) -> plane u rows of strip s; col sums -> plane s rows
// of strip u; unique writer per (plane,row) => atomic-free, no init needed.
__global__ __launch_bounds__(256, 3) void k_sim(const ushort* __restrict__ xb,
                                                const unsigned char* __restrict__ lab8,
                                                float2* __restrict__ ppart,
                                                int N) {
  __shared__ float cb[4 * 2 * 2 * 2 * 32];  // 4 KB [wv][tile][h][np][col]
  const int tid = threadIdx.x;
  const int lane = tid & 63;
  const int wv = tid >> 6;
  const int l31 = lane & 31, g2 = lane >> 5;

  // decode blockIdx -> (s,u) pair, u >= s, bid = u*(u+1)/2 + s
  const int bid = blockIdx.x;
  int u = (int)((sqrtf(8.0f * (float)bid + 1.0f) - 1.0f) * 0.5f);
  while ((u + 1) * (u + 2) / 2 <= bid) ++u;
  while (u * (u + 1) / 2 > bid) --u;
  const int s = bid - u * (u + 1) / 2;
  const int i0 = s * 128;   // A rows (strip)
  const int jb0 = u * 128;  // B rows (block)
  const bool offd = (u != s);

  // ---- A fragments from global (L2-hot): rows wv*32+l31 ----
  const ushort* arp = xb + (size_t)(i0 + wv * 32 + l31) * 128 + g2 * 8;
  bf16x8 af[8];
#pragma unroll
  for (int kt = 0; kt < 8; ++kt) af[kt] = *(const bf16x8*)(arp + kt * 16);

  // row labels byte-packed (C=64 < 256): word q holds rows wv*32+8q+4*g2+{0..3}
  const uint* lab32 = (const uint*)lab8;
  uint liw[4];
#pragma unroll
  for (int q = 0; q < 4; ++q)
    liw[q] = lab32[(i0 + wv * 32 + 8 * q + 4 * g2) >> 2];
  int lj[4];
#pragma unroll
  for (int t = 0; t < 2; ++t)
#pragma unroll
    for (int h = 0; h < 2; ++h) lj[t * 2 + h] = lab8[jb0 + t * 64 + h * 32 + l31];

  // B row-base pointers (same fragment layout as A)
  const ushort* brp = xb + (size_t)(jb0 + l31) * 128 + g2 * 8;

  floatx16 vneg = (floatx16)(0.0f), vpos = (floatx16)(0.0f);
#pragma unroll
  for (int tile = 0; tile < 2; ++tile) {
    const ushort* b0p = brp + (size_t)(tile * 64) * 128;       // h=0 rows
    const ushort* b1p = brp + (size_t)(tile * 64 + 32) * 128;  // h=1 rows

    floatx16 acc0 = (floatx16)(0.0f), acc1 = (floatx16)(0.0f);
    // 1-deep software prefetch over kt; loads come from L2 (~200 cy) and are
    // covered by the 2 MFMAs (16 cy issue) x 3 waves/SIMD + prefetch depth.
    bf16x8 c0 = *(const bf16x8*)(b0p);
    bf16x8 c1 = *(const bf16x8*)(b1p);
#pragma unroll
    for (int kt = 0; kt < 8; ++kt) {
      bf16x8 n0 = c0, n1 = c1;
      if (kt < 7) {
        n0 = *(const bf16x8*)(b0p + (kt + 1) * 16);
        n1 = *(const bf16x8*)(b1p + (kt + 1) * 16);
      }
      acc0 = __builtin_amdgcn_mfma_f32_32x32x16_bf16(af[kt], c0, acc0, 0, 0, 0);
      acc1 = __builtin_amdgcn_mfma_f32_32x32x16_bf16(af[kt], c1, acc1, 0, 0, 0);
      c0 = n0;
      c1 = n1;
    }

    // ---- epilogue: exp2, diag-skip, row + col accumulation ----
    if (offd) {
      float cn0 = 0.0f, cn1 = 0.0f, cp0 = 0.0f, cp1 = 0.0f;
#pragma unroll
      for (int r = 0; r < 16; ++r) {
        const int lr = (liw[r >> 2] >> ((r & 3) * 8)) & 255;
        const float e0 = EXP2F(acc0[r]);
        const float e1 = EXP2F(acc1[r]);
        const float s0 = (lr == lj[tile * 2 + 0]) ? e0 : 0.0f;
        const float s1 = (lr == lj[tile * 2 + 1]) ? e1 : 0.0f;
        vneg[r] += e0 + e1;
        vpos[r] += s0 + s1;
        cn0 += e0; cp0 += s0;
        cn1 += e1; cp1 += s1;
      }
      // column partials -> cb (per-wave slot; read after the single barrier)
      float a0 = cn0 + __shfl_xor(cn0, 32, 64);
      float b0 = cp0 + __shfl_xor(cp0, 32, 64);
      float a1 = cn1 + __shfl_xor(cn1, 32, 64);
      float b1 = cp1 + __shfl_xor(cp1, 32, 64);
      if (lane < 32) {
        cb[(((wv * 2 + tile) * 2 + 0) * 2 + 0) * 32 + l31] = a0;
        cb[(((wv * 2 + tile) * 2 + 0) * 2 + 1) * 32 + l31] = b0;
        cb[(((wv * 2 + tile) * 2 + 1) * 2 + 0) * 32 + l31] = a1;
        cb[(((wv * 2 + tile) * 2 + 1) * 2 + 1) * 32 + l31] = b1;
      }
    } else {
      const int jc0 = tile * 64 + l31;       // diag col (h=0) rel strip
      const int jc1 = tile * 64 + 32 + l31;  // h=1
#pragma unroll
      for (int r = 0; r < 16; ++r) {
        const int lr = (liw[r >> 2] >> ((r & 3) * 8)) & 255;
        const int ir = wv * 32 + (r & 3) + 8 * (r >> 2) + 4 * g2;
        float e0 = EXP2F(acc0[r]);
        float e1 = EXP2F(acc1[r]);
        if (ir == jc0) e0 = 0.0f;  // exclude self-similarity exactly
        if (ir == jc1) e1 = 0.0f;
        vneg[r] += e0 + e1;
        vpos[r] += ((lr == lj[tile * 2 + 0]) ? e0 : 0.0f) +
                   ((lr == lj[tile * 2 + 1]) ? e1 : 0.0f);
      }
    }
  }

  // ---- row flush: reduce over 32 col-lanes; one float2 store per row ----
#pragma unroll
  for (int r = 0; r < 16; ++r) {
    float n = vneg[r], p = vpos[r];
#pragma unroll
    for (int m = 1; m < 32; m <<= 1) {
      n += __shfl_xor(n, m, 64);
      p += __shfl_xor(p, m, 64);
    }
    if (l31 == 0) {
      const int row = i0 + wv * 32 + (r & 3) + 8 * (r >> 2) + 4 * g2;
      ppart[(size_t)u * N + row] = float2{n, p};
    }
  }

  // ---- col flush (off-diagonal only): plane s, rows of block u ----
  if (offd) {
    __syncthreads();  // the only barrier: cb writes visible
    if (tid < 128) {
      const int t = (tid >> 6) & 1, h = (tid >> 5) & 1, c5 = tid & 31;
      float n = 0.0f, p = 0.0f;
#pragma unroll
      for (int w = 0; w < 4; ++w) {
        n += cb[(((w * 2 + t) * 2 + h) * 2 + 0) * 32 + c5];
        p += cb[(((w * 2 + t) * 2 + h) * 2 + 1) * 32 + c5];
      }
      const int jrow = jb0 + t * 64 + h * 32 + c5;
      ppart[(size_t)s * N + jrow] = float2{n, p};
    }
  }
}

// ---------------- finalize: parallel over 32 blocks, 1 row/thread ------------
__global__ __launch_bounds__(256) void k_final(const float2* __restrict__ ppart,
                                               const unsigned char* __restrict__ lab8,
                                               double* __restrict__ partial,
                                               int N, int nstrip) {
  __shared__ int h[64];
  __shared__ double wsum[4];
  const int tid = threadIdx.x;
  if (tid < 64) h[tid] = 0;
  __syncthreads();
  for (int i = tid; i < N; i += 256) atomicAdd(&h[lab8[i] & 63], 1);
  __syncthreads();
  const int r = blockIdx.x * 256 + tid;
  double v = 0.0;
  if (r < N) {
    float n = 0.0f, p = 0.0f;
#pragma unroll 8
    for (int cc = 0; cc < nstrip; ++cc) {
      const float2 w = ppart[(size_t)cc * N + r];
      n += w.x;
      p += w.y;
    }
    const float cnt = (float)(h[lab8[r] & 63] - 1);
    v = (double)logf(n * cnt / p);
  }
#pragma unroll
  for (int m = 1; m < 64; m <<= 1) v += __shfl_xor(v, m, 64);
  if ((tid & 63) == 0) wsum[tid >> 6] = v;
  __syncthreads();
  if (tid == 0) partial[blockIdx.x] = wsum[0] + wsum[1] + wsum[2] + wsum[3];
}

__global__ __launch_bounds__(64) void k_write(const double* __restrict__ partial,
                                              float* __restrict__ out, int nfb, int N) {
  const int l = threadIdx.x;
  double v = 0.0;
  for (int i = l; i < nfb; i += 64) v += partial[i];
#pragma unroll
  for (int m = 1; m < 64; m <<= 1) v += __shfl_xor(v, m, 64);
  if (l == 0) out[0] = (float)(v / (double)N);
}

extern "C" void kernel_launch(void* const* d_in, const int* in_sizes, int n_in,
                              void* d_out, int out_size, void* d_ws, size_t ws_size,
                              hipStream_t stream) {
  const float* x = (const float*)d_in[0];
  const int* raw_label = (const int*)d_in[1];
  const int N = in_sizes[1];   // 8192
  const int nstrip = N / 128;  // 64
  char* ws = (char*)d_ws;
  ushort* xb = (ushort*)ws;                             // N*128 bf16 = 2 MB
  float2* ppart = (float2*)(ws + (size_t)N * 128 * 2);  // nstrip*N float2 = 4 MB
  unsigned char* lab8 = (unsigned char*)(ppart + (size_t)nstrip * N);  // N bytes
  double* partial = (double*)(lab8 + ((N + 7) & ~7));   // <=64 doubles
  float* out = (float*)d_out;

  const int pairs = nstrip * (nstrip + 1) / 2;  // 2080 upper-tri pairs
  const int nfb = (N + 255) / 256;              // 32 finalize blocks

  k_prep<<<dim3(N / 4), dim3(256), 0, stream>>>(x, raw_label, xb, lab8, N);
  k_sim<<<dim3(pairs), dim3(256), 0, stream>>>(xb, lab8, ppart, N);
  k_final<<<dim3(nfb), dim3(256), 0, stream>>>(ppart, lab8, partial, N, nstrip);
  k_write<<<dim3(1), dim3(64), 0, stream>>>(partial, out, nfb, N);
}